// Round 5
// baseline (29601.407 us; speedup 1.0000x reference)
//
#include <hip/hip_runtime.h>
#include <hip/hip_bf16.h>
#include <cstdint>
#include <cstddef>

constexpr int Nn = 4;       // agents
constexpr int Bb = 32768;   // batch
constexpr int Ss = 512;     // state dim
constexpr int Av = 64;      // action dim
constexpr int SA = 576;     // S + A
constexpr int RB = 4;       // batch rows per block
constexpr float BN_EPS = 1e-5f;

__device__ __forceinline__ float lrelu(float v){ return v >= 0.f ? v : 0.01f * v; }

// ---------------- BatchNorm statistics (only use of d_ws: 36.9 KB) ----------
__global__ __launch_bounds__(256) void bn_stats(const float* __restrict__ states,
                                                const float* __restrict__ actions,
                                                float* __restrict__ ssum,
                                                float* __restrict__ ssq){
  const int n = blockIdx.z;
  const int f = blockIdx.x * 64 + threadIdx.x;   // 0..575
  const int ty = threadIdx.y;
  const float* p; int step;
  if (f < Ss){ p = states  + (size_t)n*Bb*Ss + f;        step = Ss; }
  else       { p = actions + (size_t)n*Bb*Av + (f - Ss); step = Av; }
  float s = 0.f, q = 0.f;
  const int b0   = blockIdx.y * 512 + ty;
  const int bend = blockIdx.y * 512 + 512;
  for (int b = b0; b < bend; b += 4){
    float v = p[(size_t)b * step];
    s += v; q += v * v;
  }
  __shared__ float rs[4][64], rq[4][64];
  rs[ty][threadIdx.x] = s; rq[ty][threadIdx.x] = q;
  __syncthreads();
  if (ty == 0){
    s = rs[0][threadIdx.x] + rs[1][threadIdx.x] + rs[2][threadIdx.x] + rs[3][threadIdx.x];
    q = rq[0][threadIdx.x] + rq[1][threadIdx.x] + rq[2][threadIdx.x] + rq[3][threadIdx.x];
    atomicAdd(&ssum[n*SA + f], s);
    atomicAdd(&ssq [n*SA + f], q);
  }
}

__global__ void bn_finalize(const float* __restrict__ ssum, const float* __restrict__ ssq,
                            float* __restrict__ mean, float* __restrict__ rstd){
  int i = blockIdx.x * 256 + threadIdx.x;   // 9*256 = 2304 = Nn*SA
  float m = ssum[i] * (1.f / Bb);
  float v = ssq[i] * (1.f / Bb) - m * m;    // biased var, matches jnp.var
  v = fmaxf(v, 0.f);
  mean[i] = m;
  rstd[i] = rsqrtf(v + BN_EPS);
}

// -------- per-agent 4-row x 256-col GEMM, X from global with BN (fp32) ------
template<int K>
__device__ __forceinline__ void gemm4_glb(const float* __restrict__ st,
                                          const float* __restrict__ ac,
                                          const float* __restrict__ mean,
                                          const float* __restrict__ rstd,
                                          int a, int brow0, int tid,
                                          const float* __restrict__ W,
                                          const float* __restrict__ bias, bool act,
                                          float (*Xs)[68], float (*Wt)[264],
                                          float (*Sout)[256]){
  const int r = tid >> 6, c4 = (tid & 63) * 4;
  float acc[4] = {};
  for (int k0 = 0; k0 < K; k0 += 8){
    if (tid < 32){
      const int rb = tid >> 3, kq = tid & 7;
      const int f = k0 + kq;
      float v = (f < Ss) ? st[((size_t)a*Bb + brow0 + rb)*Ss + f]
                         : ac[((size_t)a*Bb + brow0 + rb)*Av + (f - Ss)];
      Xs[kq][rb] = (v - mean[a*SA + f]) * rstd[a*SA + f];
    }
    {
      const int wk = tid >> 5, wc = (tid & 31) * 8;
      const float* wp = W + (size_t)(k0 + wk) * 256 + wc;
      *(float4*)&Wt[wk][wc]     = *(const float4*)wp;
      *(float4*)&Wt[wk][wc + 4] = *(const float4*)(wp + 4);
    }
    __syncthreads();
    #pragma unroll
    for (int kk = 0; kk < 8; kk++){
      const float av = Xs[kk][r];
      float4 w = *(const float4*)&Wt[kk][c4];
      acc[0] += av * w.x; acc[1] += av * w.y; acc[2] += av * w.z; acc[3] += av * w.w;
    }
    __syncthreads();
  }
  float4 o;
  o.x = acc[0] + (bias ? bias[c4 + 0] : 0.f);
  o.y = acc[1] + (bias ? bias[c4 + 1] : 0.f);
  o.z = acc[2] + (bias ? bias[c4 + 2] : 0.f);
  o.w = acc[3] + (bias ? bias[c4 + 3] : 0.f);
  if (act){ o.x = lrelu(o.x); o.y = lrelu(o.y); o.z = lrelu(o.z); o.w = lrelu(o.w); }
  *(float4*)&Sout[a*RB + r][c4] = o;
  // no trailing barrier; callers barrier before next read of Sout
}

// -------- per-agent 4-row x 256-col GEMM, X from LDS (optionally concat) ----
// Sout may alias S1: all reads complete at the post-MAC barrier of the last
// k-tile before any thread writes.
template<int K, bool HEAD>
__device__ __forceinline__ void gemm4_lds(const float (*S1)[256], const float (*S2)[256],
                                          int a, int tid,
                                          const float* __restrict__ W,
                                          const float* __restrict__ bias, bool act,
                                          float (*Wt)[264], float (*Sout)[256]){
  const int r = tid >> 6, c4 = (tid & 63) * 4;
  float acc[4] = {};
  for (int k0 = 0; k0 < K; k0 += 8){
    if (HEAD){
      // W: [16 heads][256 k][16 d]; LDS col = e*16 + d
      const int wk = tid >> 5, c8 = (tid & 31) * 8;
      const int e = c8 >> 4, d0 = c8 & 15;   // d0 in {0, 8}
      const float* wp = W + (size_t)e * (256 * 16) + (size_t)(k0 + wk) * 16 + d0;
      *(float4*)&Wt[wk][c8]     = *(const float4*)wp;
      *(float4*)&Wt[wk][c8 + 4] = *(const float4*)(wp + 4);
    } else {
      const int wk = tid >> 5, wc = (tid & 31) * 8;
      const float* wp = W + (size_t)(k0 + wk) * 256 + wc;
      *(float4*)&Wt[wk][wc]     = *(const float4*)wp;
      *(float4*)&Wt[wk][wc + 4] = *(const float4*)(wp + 4);
    }
    __syncthreads();
    const float (*src)[256] = (k0 < 256) ? S1 : S2;
    const int kb = (k0 < 256) ? k0 : k0 - 256;
    const float* arow = &src[a*RB + r][kb];
    #pragma unroll
    for (int kk = 0; kk < 8; kk++){
      const float av = arow[kk];
      float4 w = *(const float4*)&Wt[kk][c4];
      acc[0] += av * w.x; acc[1] += av * w.y; acc[2] += av * w.z; acc[3] += av * w.w;
    }
    __syncthreads();
  }
  float4 o;
  o.x = acc[0] + (bias ? bias[c4 + 0] : 0.f);
  o.y = acc[1] + (bias ? bias[c4 + 1] : 0.f);
  o.z = acc[2] + (bias ? bias[c4 + 2] : 0.f);
  o.w = acc[3] + (bias ? bias[c4 + 3] : 0.f);
  if (act){ o.x = lrelu(o.x); o.y = lrelu(o.y); o.z = lrelu(o.z); o.w = lrelu(o.w); }
  *(float4*)&Sout[a*RB + r][c4] = o;
}

// ---------------- fully fused pipeline: 4 batch rows x 4 agents per block ---
__global__ __launch_bounds__(256) void fused(
    const float* __restrict__ states, const float* __restrict__ actions,
    const float* __restrict__ mean,  const float* __restrict__ rstd,
    const float* __restrict__ Wenc, const float* __restrict__ benc,
    const float* __restrict__ Wsx,  const float* __restrict__ bsx,
    const float* __restrict__ Wk,   const float* __restrict__ Wsel,
    const float* __restrict__ Wv,   const float* __restrict__ bv,
    const float* __restrict__ Wc1,  const float* __restrict__ bc1,
    const float* __restrict__ Wc2,  const float* __restrict__ bc2,
    float* __restrict__ qout){
  __shared__ float A [16][256];   // s_enc -> sa_enc -> vals -> s_enc(recomp)
  __shared__ float Bs[16][256];   // keys -> h
  __shared__ float C [16][256];   // sel -> other
  __shared__ float Wt[8][264];
  __shared__ float Xs[8][68];
  __shared__ float Cq[4][68];

  const int tid   = threadIdx.x;
  const int brow0 = blockIdx.x * RB;

  // 1) s_enc -> A
  for (int a = 0; a < Nn; a++)
    gemm4_glb<Ss>(states, actions, mean, rstd, a, brow0, tid,
                  Wsx + (size_t)a*Ss*256, bsx + a*256, true, Xs, Wt, A);
  __syncthreads();
  // 2) sel = s_enc @ Wsel -> C  (no bias, no act)
  for (int a = 0; a < Nn; a++)
    gemm4_lds<256, true>(A, nullptr, a, tid, Wsel, nullptr, false, Wt, C);
  __syncthreads();
  // 3) sa_enc -> A (s_enc reads done)
  for (int a = 0; a < Nn; a++)
    gemm4_glb<SA>(states, actions, mean, rstd, a, brow0, tid,
                  Wenc + (size_t)a*SA*256, benc + a*256, true, Xs, Wt, A);
  __syncthreads();
  // 4) keys = sa_enc @ Wk -> Bs
  for (int a = 0; a < Nn; a++)
    gemm4_lds<256, true>(A, nullptr, a, tid, Wk, nullptr, false, Wt, Bs);
  __syncthreads();
  // 5) vals = lrelu(sa_enc @ Wv + bv) -> A in place
  for (int a = 0; a < Nn; a++)
    gemm4_lds<256, true>(A, nullptr, a, tid, Wv, bv, true, Wt, A);
  __syncthreads();

  // 6) attention: sel(C), keys(Bs), vals(A) -> other (in place over C).
  // Each thread owns slice (rb, e) for ALL agents: reads and writes only its
  // own slice -> race-free without a barrier inside.
  if (tid < 64){
    const int rb = tid >> 4, e = tid & 15;
    const int co = e * 16;
    float S[4][16], Kf[4][16], Vf[4][16];
    #pragma unroll
    for (int i = 0; i < 4; i++)
      #pragma unroll
      for (int l = 0; l < 16; l++){
        S[i][l]  = C [i*RB + rb][co + l];
        Kf[i][l] = Bs[i*RB + rb][co + l];
        Vf[i][l] = A [i*RB + rb][co + l];
      }
    #pragma unroll
    for (int i = 0; i < 4; i++){
      float lg[4];
      #pragma unroll
      for (int j = 0; j < 4; j++){
        float d = 0.f;
        #pragma unroll
        for (int l = 0; l < 16; l++) d += S[i][l] * Kf[j][l];
        lg[j] = d * 0.25f;                  // / sqrt(D=16)
      }
      lg[i] = -1e9f;                        // self mask
      float m = fmaxf(fmaxf(lg[0], lg[1]), fmaxf(lg[2], lg[3]));
      float p[4], s = 0.f;
      #pragma unroll
      for (int j = 0; j < 4; j++){ p[j] = expf(lg[j] - m); s += p[j]; }
      p[i] = 0.f;
      const float inv = 1.f / s;
      float o[16] = {};
      #pragma unroll
      for (int j = 0; j < 4; j++){
        const float pj = p[j] * inv;
        #pragma unroll
        for (int l = 0; l < 16; l++) o[l] += pj * Vf[j][l];
      }
      #pragma unroll
      for (int l = 0; l < 16; l++) C[i*RB + rb][co + l] = o[l];
    }
  }
  __syncthreads();

  // 7) s_enc recompute -> A (vals dead)
  for (int a = 0; a < Nn; a++)
    gemm4_glb<Ss>(states, actions, mean, rstd, a, brow0, tid,
                  Wsx + (size_t)a*Ss*256, bsx + a*256, true, Xs, Wt, A);
  __syncthreads();
  // 8) h = lrelu([s_enc | other] @ Wc1 + bc1) -> Bs (keys dead)
  for (int a = 0; a < Nn; a++)
    gemm4_lds<512, false>(A, C, a, tid, Wc1 + (size_t)a*512*256, bc1 + a*256, true, Wt, Bs);
  __syncthreads();

  // 9) critic2 + argmax(actions) select
  for (int a = 0; a < Nn; a++){
    const int r2 = tid >> 6, c2 = tid & 63;
    float acc = 0.f;
    for (int k0 = 0; k0 < 256; k0 += 8){
      const int wk = tid >> 5, wc = (tid & 31) * 2;
      const float* wp = Wc2 + (size_t)a*256*64 + (size_t)(k0 + wk)*64 + wc;
      Wt[wk][wc]     = wp[0];
      Wt[wk][wc + 1] = wp[1];
      __syncthreads();
      #pragma unroll
      for (int kk = 0; kk < 8; kk++) acc += Bs[a*RB + r2][k0 + kk] * Wt[kk][c2];
      __syncthreads();
    }
    Cq[r2][c2] = acc + bc2[a*64 + c2];
    __syncthreads();
    if (tid < RB){
      const float* ap = actions + ((size_t)a*Bb + brow0 + tid)*Av;
      float best = ap[0]; int bi = 0;
      for (int j = 1; j < Av; j++){
        float v = ap[j];
        if (v > best){ best = v; bi = j; }   // first max, matches jnp.argmax
      }
      qout[(size_t)a*Bb + brow0 + tid] = Cq[tid][bi];
    }
    __syncthreads();
  }
}

extern "C" void kernel_launch(void* const* d_in, const int* in_sizes, int n_in,
                              void* d_out, int out_size, void* d_ws, size_t ws_size,
                              hipStream_t stream){
  (void)in_sizes; (void)n_in; (void)out_size; (void)ws_size;
  const float* states  = (const float*)d_in[0];
  const float* actions = (const float*)d_in[1];
  const float* Wenc    = (const float*)d_in[2];
  const float* benc    = (const float*)d_in[3];
  const float* Wsx     = (const float*)d_in[4];
  const float* bsx     = (const float*)d_in[5];
  const float* Wk      = (const float*)d_in[6];
  const float* Wsel    = (const float*)d_in[7];
  const float* Wv      = (const float*)d_in[8];
  const float* bv      = (const float*)d_in[9];
  const float* Wc1     = (const float*)d_in[10];
  const float* bc1     = (const float*)d_in[11];
  const float* Wc2     = (const float*)d_in[12];
  const float* bc2     = (const float*)d_in[13];
  float* qout = (float*)d_out;

  // d_ws: 4 * Nn*SA floats = 36.9 KB total
  float* ssum = (float*)d_ws;
  float* ssq  = ssum + Nn*SA;
  float* mean = ssq  + Nn*SA;
  float* rstd = mean + Nn*SA;

  hipMemsetAsync(ssum, 0, 2*Nn*SA*sizeof(float), stream);
  bn_stats<<<dim3(9, 64, Nn), dim3(64, 4), 0, stream>>>(states, actions, ssum, ssq);
  bn_finalize<<<dim3(9), dim3(256), 0, stream>>>(ssum, ssq, mean, rstd);

  fused<<<dim3(Bb/RB), dim3(256), 0, stream>>>(states, actions, mean, rstd,
                                               Wenc, benc, Wsx, bsx,
                                               Wk, Wsel, Wv, bv,
                                               Wc1, bc1, Wc2, bc2, qout);
}

// Round 6
// 2075.020 us; speedup vs baseline: 14.2656x; 14.2656x over previous
//
#include <hip/hip_runtime.h>
#include <hip/hip_bf16.h>
#include <cstdint>
#include <cstddef>

using bf16 = __hip_bfloat16;
typedef __attribute__((ext_vector_type(8))) short bf16x8v;
typedef __attribute__((ext_vector_type(4))) float f32x4v;

constexpr int Nn = 4;       // agents
constexpr int Bb = 32768;   // batch
constexpr int Ss = 512;     // state dim
constexpr int Av = 64;      // action dim
constexpr int SA = 576;     // S + A
constexpr float BN_EPS = 1e-5f;

__device__ __forceinline__ float lrelu(float v){ return v >= 0.f ? v : 0.01f * v; }
__device__ __forceinline__ float bf2f(bf16 x){ return __bfloat162float(x); }
__device__ __forceinline__ short f2bf(float v){
  union { bf16 b; short s; } u; u.b = __float2bfloat16(v); return u.s;
}

// ---------------- BatchNorm statistics ----------------
__global__ __launch_bounds__(256) void bn_stats(const float* __restrict__ states,
                                                const float* __restrict__ actions,
                                                float* __restrict__ ssum,
                                                float* __restrict__ ssq){
  const int n = blockIdx.z;
  const int f = blockIdx.x * 64 + threadIdx.x;
  const int ty = threadIdx.y;
  const float* p; int step;
  if (f < Ss){ p = states  + (size_t)n*Bb*Ss + f;        step = Ss; }
  else       { p = actions + (size_t)n*Bb*Av + (f - Ss); step = Av; }
  float s = 0.f, q = 0.f;
  const int b0 = blockIdx.y * 512 + ty, bend = blockIdx.y * 512 + 512;
  for (int b = b0; b < bend; b += 4){
    float v = p[(size_t)b * step];
    s += v; q += v * v;
  }
  __shared__ float rs[4][64], rq[4][64];
  rs[ty][threadIdx.x] = s; rq[ty][threadIdx.x] = q;
  __syncthreads();
  if (ty == 0){
    s = rs[0][threadIdx.x] + rs[1][threadIdx.x] + rs[2][threadIdx.x] + rs[3][threadIdx.x];
    q = rq[0][threadIdx.x] + rq[1][threadIdx.x] + rq[2][threadIdx.x] + rq[3][threadIdx.x];
    atomicAdd(&ssum[n*SA + f], s);
    atomicAdd(&ssq [n*SA + f], q);
  }
}

__global__ void bn_finalize(const float* __restrict__ ssum, const float* __restrict__ ssq,
                            float* __restrict__ mean, float* __restrict__ rstd){
  int i = blockIdx.x * 256 + threadIdx.x;
  float m = ssum[i] * (1.f / Bb);
  float v = ssq[i] * (1.f / Bb) - m * m;
  v = fmaxf(v, 0.f);
  mean[i] = m;
  rstd[i] = rsqrtf(v + BN_EPS);
}

// ---------------- weight prep: transpose to [n][K] bf16, optional BN fold ---
// plain: dst[a][c][f] = src[a][f][c] * (scale?scale[a*SA+f]:1)
// head : dst[c][f] = src[e=c>>4][f][d=c&15]   (shared across agents)
// bias fold: bias_out[a][c] = bias_in[a][c] - sum_f mean[a*SA+f]*w'
__global__ void foldT(const float* __restrict__ src, const float* __restrict__ scale,
                      const float* __restrict__ mean, const float* __restrict__ bias_in,
                      float* __restrict__ bias_out, short* __restrict__ dst,
                      int K, int N, int head){
  const int a = blockIdx.y;
  const int c = blockIdx.x * 64 + threadIdx.x;
  if (c >= N) return;
  const float* s = src + (head ? 0 : (size_t)a*K*N);
  short* d = dst + (head ? 0 : (size_t)a*K*N) + (size_t)c*K;
  float bsum = 0.f;
  for (int f = 0; f < K; f++){
    float w = head ? s[(((size_t)(c >> 4))*K + f)*16 + (c & 15)]
                   : s[(size_t)f*N + c];
    if (scale) w *= scale[a*SA + f];
    if (mean)  bsum += mean[a*SA + f] * w;
    d[f] = f2bf(w);
  }
  if (bias_out) bias_out[a*N + c] = bias_in[a*N + c] - bsum;
}

// ---------------- MFMA GEMM -------------------------------------------------
// C[a*Bb+row][col] = act( A[row][0..K) @ W'[col][0..K)^T + bias )
// W' layout: [col][K] bf16 (k-contiguous), per-agent stride wPerAgent elems.
// ASRC: 0 fp32 concat states(512)|actions(64); 1 fp32 pitch 512;
//       2 bf16 pitch 256; 3 bf16 concat A1|A2 both pitch 256.
// Tiles: BM x BN, 256 threads = 4 waves as WM x WN grid, 16x16x32 mfma frags.
template<int BM,int BN,int WM,int WN,int K,int ASRC,bool ACT,bool OUTF32>
__global__ __launch_bounds__(256) void mgemm(const void* A1, const void* A2,
                                             const short* __restrict__ Wp, int wPerAgent,
                                             const float* __restrict__ bias, int biasStride,
                                             void* Out, int outPitch){
  __shared__ __align__(16) short As[BM*40];
  __shared__ __align__(16) short Bs[BN*40];
  const int tid  = threadIdx.x;
  const int a    = blockIdx.z;
  const int row0 = blockIdx.x * BM;
  const int col0 = blockIdx.y * BN;
  const short* Wb = Wp + (size_t)a * wPerAgent;
  constexpr int FM = BM/WM/16, FN = BN/WN/16;
  const int wid = tid >> 6, lane = tid & 63;
  const int wm = wid % WM, wn = wid / WM;
  const int rowB = wm*(BM/WM), colB = wn*(BN/WN);
  const int lrow = lane & 15, lq = lane >> 4;

  f32x4v acc[FM][FN];
  #pragma unroll
  for (int i = 0; i < FM; i++)
    #pragma unroll
    for (int j = 0; j < FN; j++) acc[i][j] = (f32x4v){0.f,0.f,0.f,0.f};

  for (int k0 = 0; k0 < K; k0 += 32){
    // ---- stage A tile (BM x 32) ----
    {
      constexpr int EA = BM/8;           // elems per thread (16 or 8)
      int r, kq;
      if constexpr (BM == 128){ r = tid >> 1; kq = (tid & 1)*16; }
      else                    { r = tid >> 2; kq = (tid & 3)*8;  }
      const size_t grow = (size_t)a*Bb + row0 + r;
      #pragma unroll
      for (int c8 = 0; c8 < EA; c8 += 8){
        const int f = k0 + kq + c8;       // multiple of 8; never crosses 512/256 splits
        if constexpr (ASRC == 0 || ASRC == 1){
          const float* sp;
          if constexpr (ASRC == 0)
            sp = (f < 512) ? (const float*)A1 + grow*512 + f
                           : (const float*)A2 + grow*64 + (f - 512);
          else
            sp = (const float*)A1 + grow*512 + f;
          float4 x0 = *(const float4*)sp;
          float4 x1 = *(const float4*)(sp + 4);
          short tmp[8] = { f2bf(x0.x), f2bf(x0.y), f2bf(x0.z), f2bf(x0.w),
                           f2bf(x1.x), f2bf(x1.y), f2bf(x1.z), f2bf(x1.w) };
          *(bf16x8v*)&As[r*40 + kq + c8] = *(bf16x8v*)tmp;
        } else {
          const short* sp;
          if constexpr (ASRC == 3)
            sp = (f < 256) ? (const short*)A1 + grow*256 + f
                           : (const short*)A2 + grow*256 + (f - 256);
          else
            sp = (const short*)A1 + grow*256 + f;
          *(bf16x8v*)&As[r*40 + kq + c8] = *(const bf16x8v*)sp;
        }
      }
    }
    // ---- stage B tile (BN x 32) from W'[col][k] ----
    {
      int n, kq, reps;
      if constexpr      (BN == 256){ n = tid;      kq = 0;            reps = 4; }
      else if constexpr (BN == 128){ n = tid >> 1; kq = (tid & 1)*16; reps = 2; }
      else                         { n = tid >> 2; kq = (tid & 3)*8;  reps = 1; }
      const short* wp = Wb + (size_t)(col0 + n)*K + k0 + kq;
      #pragma unroll
      for (int t = 0; t < reps; t++)
        *(bf16x8v*)&Bs[n*40 + kq + t*8] = *(const bf16x8v*)(wp + t*8);
    }
    __syncthreads();
    // ---- fragments + MFMA ----
    bf16x8v af[FM], bfr[FN];
    #pragma unroll
    for (int mi = 0; mi < FM; mi++)
      af[mi] = *(const bf16x8v*)&As[(rowB + mi*16 + lrow)*40 + lq*8];
    #pragma unroll
    for (int ni = 0; ni < FN; ni++)
      bfr[ni] = *(const bf16x8v*)&Bs[(colB + ni*16 + lrow)*40 + lq*8];
    #pragma unroll
    for (int mi = 0; mi < FM; mi++)
      #pragma unroll
      for (int ni = 0; ni < FN; ni++)
        acc[mi][ni] = __builtin_amdgcn_mfma_f32_16x16x32_bf16(af[mi], bfr[ni], acc[mi][ni], 0, 0, 0);
    __syncthreads();
  }
  // ---- epilogue: C/D layout col=lane&15, row=quad*4+reg (m89/m91) ----
  #pragma unroll
  for (int mi = 0; mi < FM; mi++){
    const size_t gr = (size_t)a*Bb + row0 + rowB + mi*16 + lq*4;
    #pragma unroll
    for (int ni = 0; ni < FN; ni++){
      const int gc = col0 + colB + ni*16 + lrow;
      const float bb = bias ? bias[a*biasStride + gc] : 0.f;
      #pragma unroll
      for (int r = 0; r < 4; r++){
        float v = acc[mi][ni][r] + bb;
        if (ACT) v = lrelu(v);
        if constexpr (OUTF32) ((float*)Out)[(gr + r)*(size_t)outPitch + gc] = v;
        else                  ((bf16*) Out)[(gr + r)*(size_t)outPitch + gc] = __float2bfloat16(v);
      }
    }
  }
}

// ---------------- attention (bf16 global, in place over sel) ----------------
union B8g { uint4 u; bf16 h[8]; };
__global__ __launch_bounds__(256) void attn_g(const bf16* __restrict__ K_,
                                              const bf16* __restrict__ V_,
                                              bf16* SO){
  const int t = blockIdx.x * 256 + threadIdx.x;   // (b*16 + e)
  const int e = t & 15;
  const size_t b = t >> 4;
  const size_t ofs = b*256 + e*16;
  float S[4][16], Kf[4][16], Vf[4][16];
  #pragma unroll
  for (int i = 0; i < 4; i++){
    B8g u0, u1;
    const bf16* sp = SO + (size_t)i*Bb*256 + ofs;
    u0.u = *(const uint4*)sp; u1.u = *(const uint4*)(sp + 8);
    #pragma unroll
    for (int l = 0; l < 8; l++){ S[i][l] = bf2f(u0.h[l]); S[i][8+l] = bf2f(u1.h[l]); }
    const bf16* kp = K_ + (size_t)i*Bb*256 + ofs;
    u0.u = *(const uint4*)kp; u1.u = *(const uint4*)(kp + 8);
    #pragma unroll
    for (int l = 0; l < 8; l++){ Kf[i][l] = bf2f(u0.h[l]); Kf[i][8+l] = bf2f(u1.h[l]); }
    const bf16* vp = V_ + (size_t)i*Bb*256 + ofs;
    u0.u = *(const uint4*)vp; u1.u = *(const uint4*)(vp + 8);
    #pragma unroll
    for (int l = 0; l < 8; l++){ Vf[i][l] = bf2f(u0.h[l]); Vf[i][8+l] = bf2f(u1.h[l]); }
  }
  #pragma unroll
  for (int i = 0; i < 4; i++){
    float lg[4];
    #pragma unroll
    for (int j = 0; j < 4; j++){
      float d = 0.f;
      #pragma unroll
      for (int l = 0; l < 16; l++) d += S[i][l] * Kf[j][l];
      lg[j] = d * 0.25f;                 // / sqrt(16)
    }
    lg[i] = -1e9f;
    float m = fmaxf(fmaxf(lg[0], lg[1]), fmaxf(lg[2], lg[3]));
    float p[4], s = 0.f;
    #pragma unroll
    for (int j = 0; j < 4; j++){ p[j] = expf(lg[j] - m); s += p[j]; }
    p[i] = 0.f;
    const float inv = 1.f / s;
    float o[16] = {};
    #pragma unroll
    for (int j = 0; j < 4; j++){
      const float pj = p[j] * inv;
      #pragma unroll
      for (int l = 0; l < 16; l++) o[l] += pj * Vf[j][l];
    }
    B8g w0, w1;
    #pragma unroll
    for (int l = 0; l < 8; l++){ w0.h[l] = __float2bfloat16(o[l]); w1.h[l] = __float2bfloat16(o[8+l]); }
    bf16* op = SO + (size_t)i*Bb*256 + ofs;
    *(uint4*)op       = w0.u;
    *(uint4*)(op + 8) = w1.u;
  }
}

// ---------------- argmax(actions) gather ------------------------------------
__global__ __launch_bounds__(256) void sel_q(const float* __restrict__ actions,
                                             const float* __restrict__ allq,
                                             float* __restrict__ out){
  const size_t i = (size_t)blockIdx.x * 256 + threadIdx.x;  // row = a*Bb + b
  const float* ap = actions + i*64;
  float best = ap[0]; int bi = 0;
  for (int j = 1; j < 64; j++){
    float v = ap[j];
    if (v > best){ best = v; bi = j; }   // first max, matches jnp.argmax
  }
  out[i] = allq[i*64 + bi];
}

// ================= fallback (round-5 verified fused pipeline) ================
constexpr int RB = 4;

template<int K>
__device__ __forceinline__ void gemm4_glb(const float* __restrict__ st,
                                          const float* __restrict__ ac,
                                          const float* __restrict__ mean,
                                          const float* __restrict__ rstd,
                                          int a, int brow0, int tid,
                                          const float* __restrict__ W,
                                          const float* __restrict__ bias, bool act,
                                          float (*Xs)[68], float (*Wt)[264],
                                          float (*Sout)[256]){
  const int r = tid >> 6, c4 = (tid & 63) * 4;
  float acc[4] = {};
  for (int k0 = 0; k0 < K; k0 += 8){
    if (tid < 32){
      const int rb = tid >> 3, kq = tid & 7;
      const int f = k0 + kq;
      float v = (f < Ss) ? st[((size_t)a*Bb + brow0 + rb)*Ss + f]
                         : ac[((size_t)a*Bb + brow0 + rb)*Av + (f - Ss)];
      Xs[kq][rb] = (v - mean[a*SA + f]) * rstd[a*SA + f];
    }
    {
      const int wk = tid >> 5, wc = (tid & 31) * 8;
      const float* wp = W + (size_t)(k0 + wk) * 256 + wc;
      *(float4*)&Wt[wk][wc]     = *(const float4*)wp;
      *(float4*)&Wt[wk][wc + 4] = *(const float4*)(wp + 4);
    }
    __syncthreads();
    #pragma unroll
    for (int kk = 0; kk < 8; kk++){
      const float av = Xs[kk][r];
      float4 w = *(const float4*)&Wt[kk][c4];
      acc[0] += av*w.x; acc[1] += av*w.y; acc[2] += av*w.z; acc[3] += av*w.w;
    }
    __syncthreads();
  }
  float4 o;
  o.x = acc[0] + (bias ? bias[c4+0] : 0.f);
  o.y = acc[1] + (bias ? bias[c4+1] : 0.f);
  o.z = acc[2] + (bias ? bias[c4+2] : 0.f);
  o.w = acc[3] + (bias ? bias[c4+3] : 0.f);
  if (act){ o.x = lrelu(o.x); o.y = lrelu(o.y); o.z = lrelu(o.z); o.w = lrelu(o.w); }
  *(float4*)&Sout[a*RB + r][c4] = o;
}

template<int K, bool HEAD>
__device__ __forceinline__ void gemm4_lds(const float (*S1)[256], const float (*S2)[256],
                                          int a, int tid,
                                          const float* __restrict__ W,
                                          const float* __restrict__ bias, bool act,
                                          float (*Wt)[264], float (*Sout)[256]){
  const int r = tid >> 6, c4 = (tid & 63) * 4;
  float acc[4] = {};
  for (int k0 = 0; k0 < K; k0 += 8){
    if (HEAD){
      const int wk = tid >> 5, c8 = (tid & 31) * 8;
      const int e = c8 >> 4, d0 = c8 & 15;
      const float* wp = W + (size_t)e*(256*16) + (size_t)(k0 + wk)*16 + d0;
      *(float4*)&Wt[wk][c8]     = *(const float4*)wp;
      *(float4*)&Wt[wk][c8 + 4] = *(const float4*)(wp + 4);
    } else {
      const int wk = tid >> 5, wc = (tid & 31) * 8;
      const float* wp = W + (size_t)(k0 + wk)*256 + wc;
      *(float4*)&Wt[wk][wc]     = *(const float4*)wp;
      *(float4*)&Wt[wk][wc + 4] = *(const float4*)(wp + 4);
    }
    __syncthreads();
    const float (*src)[256] = (k0 < 256) ? S1 : S2;
    const int kb = (k0 < 256) ? k0 : k0 - 256;
    const float* arow = &src[a*RB + r][kb];
    #pragma unroll
    for (int kk = 0; kk < 8; kk++){
      const float av = arow[kk];
      float4 w = *(const float4*)&Wt[kk][c4];
      acc[0] += av*w.x; acc[1] += av*w.y; acc[2] += av*w.z; acc[3] += av*w.w;
    }
    __syncthreads();
  }
  float4 o;
  o.x = acc[0] + (bias ? bias[c4+0] : 0.f);
  o.y = acc[1] + (bias ? bias[c4+1] : 0.f);
  o.z = acc[2] + (bias ? bias[c4+2] : 0.f);
  o.w = acc[3] + (bias ? bias[c4+3] : 0.f);
  if (act){ o.x = lrelu(o.x); o.y = lrelu(o.y); o.z = lrelu(o.z); o.w = lrelu(o.w); }
  *(float4*)&Sout[a*RB + r][c4] = o;
}

__global__ __launch_bounds__(256) void fused(
    const float* __restrict__ states, const float* __restrict__ actions,
    const float* __restrict__ mean,  const float* __restrict__ rstd,
    const float* __restrict__ Wenc, const float* __restrict__ benc,
    const float* __restrict__ Wsx,  const float* __restrict__ bsx,
    const float* __restrict__ Wk,   const float* __restrict__ Wsel,
    const float* __restrict__ Wv,   const float* __restrict__ bv,
    const float* __restrict__ Wc1,  const float* __restrict__ bc1,
    const float* __restrict__ Wc2,  const float* __restrict__ bc2,
    float* __restrict__ qout){
  __shared__ float A [16][256];
  __shared__ float Bs2[16][256];
  __shared__ float C [16][256];
  __shared__ float Wt[8][264];
  __shared__ float Xs[8][68];
  __shared__ float Cq[4][68];
  const int tid   = threadIdx.x;
  const int brow0 = blockIdx.x * RB;
  for (int a = 0; a < Nn; a++)
    gemm4_glb<Ss>(states, actions, mean, rstd, a, brow0, tid,
                  Wsx + (size_t)a*Ss*256, bsx + a*256, true, Xs, Wt, A);
  __syncthreads();
  for (int a = 0; a < Nn; a++)
    gemm4_lds<256, true>(A, nullptr, a, tid, Wsel, nullptr, false, Wt, C);
  __syncthreads();
  for (int a = 0; a < Nn; a++)
    gemm4_glb<SA>(states, actions, mean, rstd, a, brow0, tid,
                  Wenc + (size_t)a*SA*256, benc + a*256, true, Xs, Wt, A);
  __syncthreads();
  for (int a = 0; a < Nn; a++)
    gemm4_lds<256, true>(A, nullptr, a, tid, Wk, nullptr, false, Wt, Bs2);
  __syncthreads();
  for (int a = 0; a < Nn; a++)
    gemm4_lds<256, true>(A, nullptr, a, tid, Wv, bv, true, Wt, A);
  __syncthreads();
  if (tid < 64){
    const int rb = tid >> 4, e = tid & 15;
    const int co = e * 16;
    float S[4][16], Kf[4][16], Vf[4][16];
    #pragma unroll
    for (int i = 0; i < 4; i++)
      #pragma unroll
      for (int l = 0; l < 16; l++){
        S[i][l]  = C  [i*RB + rb][co + l];
        Kf[i][l] = Bs2[i*RB + rb][co + l];
        Vf[i][l] = A  [i*RB + rb][co + l];
      }
    #pragma unroll
    for (int i = 0; i < 4; i++){
      float lg[4];
      #pragma unroll
      for (int j = 0; j < 4; j++){
        float d = 0.f;
        #pragma unroll
        for (int l = 0; l < 16; l++) d += S[i][l] * Kf[j][l];
        lg[j] = d * 0.25f;
      }
      lg[i] = -1e9f;
      float m = fmaxf(fmaxf(lg[0], lg[1]), fmaxf(lg[2], lg[3]));
      float p[4], s = 0.f;
      #pragma unroll
      for (int j = 0; j < 4; j++){ p[j] = expf(lg[j] - m); s += p[j]; }
      p[i] = 0.f;
      const float inv = 1.f / s;
      float o[16] = {};
      #pragma unroll
      for (int j = 0; j < 4; j++){
        const float pj = p[j] * inv;
        #pragma unroll
        for (int l = 0; l < 16; l++) o[l] += pj * Vf[j][l];
      }
      #pragma unroll
      for (int l = 0; l < 16; l++) C[i*RB + rb][co + l] = o[l];
    }
  }
  __syncthreads();
  for (int a = 0; a < Nn; a++)
    gemm4_glb<Ss>(states, actions, mean, rstd, a, brow0, tid,
                  Wsx + (size_t)a*Ss*256, bsx + a*256, true, Xs, Wt, A);
  __syncthreads();
  for (int a = 0; a < Nn; a++)
    gemm4_lds<512, false>(A, C, a, tid, Wc1 + (size_t)a*512*256, bc1 + a*256, true, Wt, Bs2);
  __syncthreads();
  for (int a = 0; a < Nn; a++){
    const int r2 = tid >> 6, c2 = tid & 63;
    float acc = 0.f;
    for (int k0 = 0; k0 < 256; k0 += 8){
      const int wk = tid >> 5, wc = (tid & 31) * 2;
      const float* wp = Wc2 + (size_t)a*256*64 + (size_t)(k0 + wk)*64 + wc;
      Wt[wk][wc]     = wp[0];
      Wt[wk][wc + 1] = wp[1];
      __syncthreads();
      #pragma unroll
      for (int kk = 0; kk < 8; kk++) acc += Bs2[a*RB + r2][k0 + kk] * Wt[kk][c2];
      __syncthreads();
    }
    Cq[r2][c2] = acc + bc2[a*64 + c2];
    __syncthreads();
    if (tid < RB){
      const float* ap = actions + ((size_t)a*Bb + brow0 + tid)*Av;
      float best = ap[0]; int bi = 0;
      for (int j = 1; j < Av; j++){
        float v = ap[j];
        if (v > best){ best = v; bi = j; }
      }
      qout[(size_t)a*Bb + brow0 + tid] = Cq[tid][bi];
    }
    __syncthreads();
  }
}

// ================= host =====================================================
extern "C" void kernel_launch(void* const* d_in, const int* in_sizes, int n_in,
                              void* d_out, int out_size, void* d_ws, size_t ws_size,
                              hipStream_t stream){
  (void)in_sizes; (void)n_in; (void)out_size;
  const float* states  = (const float*)d_in[0];
  const float* actions = (const float*)d_in[1];
  const float* Wenc    = (const float*)d_in[2];
  const float* benc    = (const float*)d_in[3];
  const float* Wsx     = (const float*)d_in[4];
  const float* bsx     = (const float*)d_in[5];
  const float* Wk      = (const float*)d_in[6];
  const float* Wsel    = (const float*)d_in[7];
  const float* Wv      = (const float*)d_in[8];
  const float* bv      = (const float*)d_in[9];
  const float* Wc1     = (const float*)d_in[10];
  const float* bc1     = (const float*)d_in[11];
  const float* Wc2     = (const float*)d_in[12];
  const float* bc2     = (const float*)d_in[13];
  float* qout = (float*)d_out;

  char* base = (char*)d_ws;
  float* ssum = (float*)base;                 // 2304 f
  float* ssq  = ssum + Nn*SA;
  float* mean = ssq  + Nn*SA;
  float* rstd = mean + Nn*SA;
  size_t off = 4*Nn*SA*sizeof(float);         // 36864
  float* benc_p = (float*)(base + off); off += 4096;
  float* bs_p   = (float*)(base + off); off += 4096;
  short* Wenc_p = (short*)(base + off); off += (size_t)Nn*SA*256*2;     // 1179648
  short* Ws_p   = (short*)(base + off); off += (size_t)Nn*Ss*256*2;     // 1048576
  short* Whk_p  = (short*)(base + off); off += 256*256*2;
  short* Whs_p  = (short*)(base + off); off += 256*256*2;
  short* Whv_p  = (short*)(base + off); off += 256*256*2;
  short* Wc1_p  = (short*)(base + off); off += (size_t)Nn*512*256*2;
  short* Wc2_p  = (short*)(base + off); off += (size_t)Nn*64*256*2;
  const size_t BUFB = (size_t)Nn*Bb*256*2;    // 67,108,864 B
  bf16* S   = (bf16*)(base + off); off += BUFB;
  bf16* SEL = (bf16*)(base + off); off += BUFB;
  bf16* E   = (bf16*)(base + off); off += BUFB;
  bf16* KB  = (bf16*)(base + off); off += BUFB;
  const size_t need = off;
  float* ALLQ = (float*)E;                    // 33.5 MB <= 67 MB, vals dead by then

  hipMemsetAsync(ssum, 0, 2*Nn*SA*sizeof(float), stream);
  bn_stats<<<dim3(9, 64, Nn), dim3(64, 4), 0, stream>>>(states, actions, ssum, ssq);
  bn_finalize<<<dim3(9), dim3(256), 0, stream>>>(ssum, ssq, mean, rstd);

  if (ws_size >= need){
    // weight prep (BN folded into enc weights)
    foldT<<<dim3(4, Nn), 64, 0, stream>>>(Wenc, rstd, mean, benc, benc_p, Wenc_p, SA, 256, 0);
    foldT<<<dim3(4, Nn), 64, 0, stream>>>(Wsx,  rstd, mean, bsx,  bs_p,   Ws_p,  Ss, 256, 0);
    foldT<<<dim3(4, 1), 64, 0, stream>>>(Wk,   nullptr, nullptr, nullptr, nullptr, Whk_p, 256, 256, 1);
    foldT<<<dim3(4, 1), 64, 0, stream>>>(Wsel, nullptr, nullptr, nullptr, nullptr, Whs_p, 256, 256, 1);
    foldT<<<dim3(4, 1), 64, 0, stream>>>(Wv,   nullptr, nullptr, nullptr, nullptr, Whv_p, 256, 256, 1);
    foldT<<<dim3(4, Nn), 64, 0, stream>>>(Wc1, nullptr, nullptr, nullptr, nullptr, Wc1_p, 512, 256, 0);
    foldT<<<dim3(1, Nn), 64, 0, stream>>>(Wc2, nullptr, nullptr, nullptr, nullptr, Wc2_p, 256, 64, 0);

    // E = sa_enc = lrelu(x @ Wenc' + benc')
    mgemm<128,128,2,2,576,0,true,false><<<dim3(Bb/128, 2, Nn), 256, 0, stream>>>(
        states, actions, Wenc_p, SA*256, benc_p, 256, E, 256);
    // S = s_enc
    mgemm<128,128,2,2,512,1,true,false><<<dim3(Bb/128, 2, Nn), 256, 0, stream>>>(
        states, nullptr, Ws_p, Ss*256, bs_p, 256, S, 256);
    // SEL = s_enc @ Wsel
    mgemm<128,128,2,2,256,2,false,false><<<dim3(Bb/128, 2, Nn), 256, 0, stream>>>(
        S, nullptr, Whs_p, 0, nullptr, 0, SEL, 256);
    // KB = keys
    mgemm<128,128,2,2,256,2,false,false><<<dim3(Bb/128, 2, Nn), 256, 0, stream>>>(
        E, nullptr, Whk_p, 0, nullptr, 0, KB, 256);
    // E = vals (in place; full-width blocks so each block reads only its rows)
    mgemm<64,256,1,4,256,2,true,false><<<dim3(Bb/64, 1, Nn), 256, 0, stream>>>(
        E, nullptr, Whv_p, 0, bv, 0, E, 256);
    // SEL = other (in place, per-thread slices)
    attn_g<<<dim3(Bb*16/256), 256, 0, stream>>>(KB, E, SEL);
    // KB = h = lrelu([S|other] @ Wc1 + bc1)   (keys dead)
    mgemm<128,128,2,2,512,3,true,false><<<dim3(Bb/128, 2, Nn), 256, 0, stream>>>(
        S, SEL, Wc1_p, 512*256, bc1, 256, KB, 256);
    // ALLQ = h @ Wc2 + bc2 (fp32)   (vals dead -> reuse E)
    mgemm<128,64,2,2,256,2,false,true><<<dim3(Bb/128, 1, Nn), 256, 0, stream>>>(
        KB, nullptr, Wc2_p, 64*256, bc2, 64, ALLQ, 64);
    // gather argmax
    sel_q<<<dim3(Nn*Bb/256), 256, 0, stream>>>(actions, ALLQ, qout);
  } else {
    // verified round-5 fallback (ws-independent beyond BN stats)
    fused<<<dim3(Bb/RB), 256, 0, stream>>>(states, actions, mean, rstd,
                                           Wenc, benc, Wsx, bsx,
                                           Wk, Wsel, Wv, bv,
                                           Wc1, bc1, Wc2, bc2, qout);
  }
}